// Round 1
// baseline (3093.446 us; speedup 1.0000x reference)
//
#include <hip/hip_runtime.h>
#include <hip/hip_bf16.h>
#include <math.h>

// Problem constants (fixed by reference): N=100000 nodes, E=1.6M edges, H=256, T=64.

static inline size_t align512(size_t x){ return (x + 511) & ~size_t(511); }

// ---------- CSR build ----------

__global__ void count_kernel(const int* __restrict__ ei, int* __restrict__ cnt, int E){
  int e = blockIdx.x*256 + threadIdx.x;
  if (e < E) atomicAdd(&cnt[ei[E + e]], 1);
}

__global__ void dis_kernel(const int* __restrict__ cnt, float* __restrict__ dis, int N){
  int i = blockIdx.x*256 + threadIdx.x;
  if (i < N) dis[i] = rsqrtf((float)cnt[i] + 1.0f);
}

__global__ void scan_block_kernel(const int* __restrict__ cnt, int* __restrict__ rp,
                                  int* __restrict__ bsum, int N){
  __shared__ int s[2][1024];
  int t = threadIdx.x; int i = blockIdx.x*1024 + t;
  int v = (i < N) ? cnt[i] : 0;
  int cur = 0; s[0][t] = v; __syncthreads();
  for (int off = 1; off < 1024; off <<= 1){
    int nxt = cur ^ 1;
    int val = s[cur][t];
    if (t >= off) val += s[cur][t - off];
    s[nxt][t] = val; cur = nxt; __syncthreads();
  }
  if (i < N) rp[i+1] = s[cur][t];
  if (t == 1023) bsum[blockIdx.x] = s[cur][1023];
}

__global__ void scan_sums_kernel(int* __restrict__ bsum, int nb){
  __shared__ int s[128];
  int t = threadIdx.x;
  if (t < nb) s[t] = bsum[t];
  __syncthreads();
  if (t == 0){ int acc = 0; for (int b = 0; b < nb; b++){ int v = s[b]; s[b] = acc; acc += v; } }
  __syncthreads();
  if (t < nb) bsum[t] = s[t];
}

__global__ void add_off_kernel(int* __restrict__ rp, const int* __restrict__ bsum,
                               int* __restrict__ cnt, int N){
  int i = blockIdx.x*256 + threadIdx.x;
  if (i < N){ rp[i+1] += bsum[i >> 10]; cnt[i] = 0; }
  if (i == 0) rp[0] = 0;
}

__global__ void fill_kernel(const int* __restrict__ ei, const int* __restrict__ rp,
                            int* __restrict__ cnt, int* __restrict__ csrc, int E){
  int e = blockIdx.x*256 + threadIdx.x;
  if (e < E){
    int s = ei[e]; int d = ei[E + e];
    int pos = rp[d] + atomicAdd(&cnt[d], 1);
    csrc[pos] = s;
  }
}

// ---------- GEMM: out[N,256] = A[N,256] @ W[256,256] (no bias) ----------
// thread = output column; 64 rows per block; A-row loads are wave-uniform -> s_load.

__global__ __launch_bounds__(256) void gemm_kernel(const float* __restrict__ A,
                                                   const float* __restrict__ W,
                                                   float* __restrict__ out, int N){
  int c = threadIdx.x;
  int r0 = blockIdx.x * 64;
  if (r0 + 64 <= N){
    const float* Ab = A + (size_t)r0 * 256;
    float acc[64];
    #pragma unroll
    for (int r = 0; r < 64; r++) acc[r] = 0.f;
    for (int k = 0; k < 256; k++){
      float w = W[(k << 8) + c];
      #pragma unroll
      for (int r = 0; r < 64; r++) acc[r] = fmaf(Ab[(size_t)r*256 + k], w, acc[r]);
    }
    float* Ob = out + (size_t)r0 * 256;
    #pragma unroll
    for (int r = 0; r < 64; r++) Ob[(size_t)r*256 + c] = acc[r];
  } else {
    for (int r = 0; r0 + r < N; r++){
      float acc = 0.f;
      for (int k = 0; k < 256; k++) acc = fmaf(A[(size_t)(r0+r)*256 + k], W[(k << 8) + c], acc);
      out[(size_t)(r0+r)*256 + c] = acc;
    }
  }
}

// ---------- GCN aggregation: out[i] = relu( sum_{e: dst=i} dis[s]*dis[i]*xw[s]
//                                           + dis[i]^2 * xw[i] + bias ) ----------
// one wave per node, lane = 4 columns (float4); no float atomics (CSR gather).

__global__ __launch_bounds__(256) void agg_kernel(const float* __restrict__ xw,
                                                  const float* __restrict__ dis,
                                                  const int* __restrict__ rp,
                                                  const int* __restrict__ csrc,
                                                  const float* __restrict__ bias,
                                                  float* __restrict__ out, int N){
  int node = blockIdx.x*4 + (threadIdx.x >> 6);
  int lane = threadIdx.x & 63;
  if (node >= N) return;
  const float4* xw4 = (const float4*)xw;
  float di = dis[node];
  float4 a = xw4[(size_t)node*64 + lane];
  float sc = di * di;
  float4 acc;
  acc.x = a.x*sc; acc.y = a.y*sc; acc.z = a.z*sc; acc.w = a.w*sc;
  int e0 = rp[node], e1 = rp[node+1];
  for (int e = e0; e < e1; e++){
    int s = csrc[e];
    float cc = dis[s] * di;
    float4 v = xw4[(size_t)s*64 + lane];
    acc.x = fmaf(v.x, cc, acc.x);
    acc.y = fmaf(v.y, cc, acc.y);
    acc.z = fmaf(v.z, cc, acc.z);
    acc.w = fmaf(v.w, cc, acc.w);
  }
  const float4* b4 = (const float4*)bias;
  float4 b = b4[lane];
  acc.x = fmaxf(acc.x + b.x, 0.f);
  acc.y = fmaxf(acc.y + b.y, 0.f);
  acc.z = fmaxf(acc.z + b.z, 0.f);
  acc.w = fmaxf(acc.w + b.w, 0.f);
  ((float4*)out)[(size_t)node*64 + lane] = acc;
}

// ---------- mean pool over ptr segments (atomic partial sums into zeroed hp) ----------

__global__ void pool_kernel(const float* __restrict__ h, const int* __restrict__ ptr,
                            float* __restrict__ hp){
  int t = blockIdx.x; int part = blockIdx.y; int c = threadIdx.x;
  int s0 = ptr[t], s1 = ptr[t+1];
  int len = s1 - s0;
  int chunk = (len + 7) / 8;
  int r0 = s0 + part*chunk;
  int r1 = min(r0 + chunk, s1);
  float acc = 0.f;
  for (int r = r0; r < r1; r++) acc += h[(size_t)r*256 + c];
  if (r1 > r0) atomicAdd(&hp[t*256 + c], acc);
}

__global__ void hp_div_kernel(float* __restrict__ hp, const int* __restrict__ ptr){
  int t = blockIdx.x; int c = threadIdx.x;
  float cf = (float)max(ptr[t+1] - ptr[t], 1);
  hp[t*256 + c] /= cf;
}

// ---------- transpose w_hh [768,256] -> w_hhT [256,768] ----------

__global__ void twhh_kernel(const float* __restrict__ w, float* __restrict__ wt){
  int idx = blockIdx.x*256 + threadIdx.x;
  if (idx < 768*256){
    int k = idx / 768, g = idx % 768;
    wt[idx] = w[g*256 + k];
  }
}

// ---------- GX[t,g] = dot(hp[t], w_ih[g]) + b_ih[g] ----------

__global__ __launch_bounds__(768) void gx_kernel(const float* __restrict__ hp,
                                                 const float* __restrict__ wih,
                                                 const float* __restrict__ bih,
                                                 float* __restrict__ gx){
  __shared__ float xs[256];
  int t = blockIdx.x; int g = threadIdx.x;
  if (g < 256) xs[g] = hp[t*256 + g];
  __syncthreads();
  float acc = bih[g];
  const float* wr = wih + (size_t)g*256;
  #pragma unroll 4
  for (int k = 0; k < 256; k++) acc = fmaf(xs[k], wr[k], acc);
  gx[t*768 + g] = acc;
}

// ---------- sequential GRU (single block, 768 threads) + classifier ----------
// thread (kq=tid/192, gq=tid%192): partial dot over k in [kq*64, kq*64+64) for
// 4 consecutive gates (float4 of w_hhT row). LDS reduce over 4 kq groups.

__global__ __launch_bounds__(768) void gru_kernel(const float* __restrict__ gx,
                                                  const float* __restrict__ wt,
                                                  const float* __restrict__ bhh,
                                                  const float* __restrict__ Wc,
                                                  const float* __restrict__ bc,
                                                  float* __restrict__ out){
  __shared__ float hs[256];
  __shared__ float pl[4*768];
  int tid = threadIdx.x;
  int kq = tid / 192;
  int gq = tid % 192;
  if (tid < 256) hs[tid] = 0.f;
  __syncthreads();
  const float4* w4 = (const float4*)wt;
  for (int t = 0; t < 64; t++){
    float4 p = make_float4(0.f, 0.f, 0.f, 0.f);
    int kb = kq * 64;
    #pragma unroll 4
    for (int kk = 0; kk < 64; kk++){
      float hk = hs[kb + kk];
      float4 w = w4[(size_t)(kb + kk)*192 + gq];
      p.x = fmaf(hk, w.x, p.x);
      p.y = fmaf(hk, w.y, p.y);
      p.z = fmaf(hk, w.z, p.z);
      p.w = fmaf(hk, w.w, p.w);
    }
    ((float4*)pl)[kq*192 + gq] = p;   // pl[kq][g]
    __syncthreads();
    float hnew = 0.f;
    if (tid < 256){
      int i = tid;
      float hr = bhh[i], hz = bhh[i+256], hn = bhh[i+512];
      #pragma unroll
      for (int q = 0; q < 4; q++){
        hr += pl[q*768 + i];
        hz += pl[q*768 + i + 256];
        hn += pl[q*768 + i + 512];
      }
      float xr = gx[t*768 + i], xz = gx[t*768 + i + 256], xn = gx[t*768 + i + 512];
      float r = 1.f/(1.f + expf(-(xr + hr)));
      float z = 1.f/(1.f + expf(-(xz + hz)));
      float n = tanhf(xn + r*hn);
      hnew = (1.f - z)*n + z*hs[i];
    }
    __syncthreads();
    if (tid < 256) hs[tid] = hnew;
    __syncthreads();
  }
  if (tid < 16){
    float acc = bc[tid];
    const float* wr = Wc + (size_t)tid*256;
    for (int k = 0; k < 256; k++) acc = fmaf(hs[k], wr[k], acc);
    out[tid] = acc;
  }
}

extern "C" void kernel_launch(void* const* d_in, const int* in_sizes, int n_in,
                              void* d_out, int out_size, void* d_ws, size_t ws_size,
                              hipStream_t stream){
  const float* x   = (const float*)d_in[0];
  const int*   ei  = (const int*)d_in[1];
  const int*   ptr = (const int*)d_in[2];
  const float* W1  = (const float*)d_in[3];
  const float* b1  = (const float*)d_in[4];
  const float* W2  = (const float*)d_in[5];
  const float* b2  = (const float*)d_in[6];
  const float* wih = (const float*)d_in[7];
  const float* whh = (const float*)d_in[8];
  const float* bih = (const float*)d_in[9];
  const float* bhh = (const float*)d_in[10];
  const float* Wc  = (const float*)d_in[11];
  const float* bc  = (const float*)d_in[12];
  float* outp = (float*)d_out;

  const int N = in_sizes[0] / 256;   // 100000
  const int E = in_sizes[1] / 2;     // 1600000

  char* w = (char*)d_ws;
  size_t off = 0;
  auto alloc = [&](size_t bytes){ void* p = w + off; off = align512(off + bytes); return p; };
  float* bufA = (float*)alloc((size_t)N*256*4);   // xw
  float* bufB = (float*)alloc((size_t)N*256*4);   // h (post-agg)
  float* dis  = (float*)alloc((size_t)N*4);
  int*   cnt  = (int*)  alloc((size_t)N*4);
  int*   rp   = (int*)  alloc((size_t)(N+1)*4);
  int*   bsum = (int*)  alloc(128*4);
  int*   csrc = (int*)  alloc((size_t)E*4);
  float* wt   = (float*)alloc((size_t)768*256*4);
  float* hp   = (float*)alloc((size_t)64*256*4);
  float* gxb  = (float*)alloc((size_t)64*768*4);
  (void)ws_size; (void)n_in; (void)out_size;

  hipMemsetAsync(cnt, 0, (size_t)N*4, stream);
  hipMemsetAsync(hp,  0, (size_t)64*256*4, stream);

  // CSR build + degree
  count_kernel<<<(E+255)/256, 256, 0, stream>>>(ei, cnt, E);
  dis_kernel<<<(N+255)/256, 256, 0, stream>>>(cnt, dis, N);
  int nb = (N + 1023) / 1024;
  scan_block_kernel<<<nb, 1024, 0, stream>>>(cnt, rp, bsum, N);
  scan_sums_kernel<<<1, 128, 0, stream>>>(bsum, nb);
  add_off_kernel<<<(N+255)/256, 256, 0, stream>>>(rp, bsum, cnt, N);
  fill_kernel<<<(E+255)/256, 256, 0, stream>>>(ei, rp, cnt, csrc, E);
  twhh_kernel<<<(768*256+255)/256, 256, 0, stream>>>(whh, wt);

  // GCN layer 1
  gemm_kernel<<<(N+63)/64, 256, 0, stream>>>(x, W1, bufA, N);
  agg_kernel<<<(N+3)/4, 256, 0, stream>>>(bufA, dis, rp, csrc, b1, bufB, N);
  // GCN layer 2
  gemm_kernel<<<(N+63)/64, 256, 0, stream>>>(bufB, W2, bufA, N);
  agg_kernel<<<(N+3)/4, 256, 0, stream>>>(bufA, dis, rp, csrc, b2, bufB, N);

  // pool + GRU + classifier
  pool_kernel<<<dim3(64, 8), 256, 0, stream>>>(bufB, ptr, hp);
  hp_div_kernel<<<64, 256, 0, stream>>>(hp, ptr);
  gx_kernel<<<64, 768, 0, stream>>>(hp, wih, bih, gxb);
  gru_kernel<<<1, 768, 0, stream>>>(gxb, wt, bhh, Wc, bc, outp);
}

// Round 2
// 1610.302 us; speedup vs baseline: 1.9210x; 1.9210x over previous
//
#include <hip/hip_runtime.h>
#include <hip/hip_bf16.h>
#include <math.h>

// Problem constants (fixed by reference): N=100000 nodes, E=1.6M edges, H=256, T=64.

static inline size_t align512(size_t x){ return (x + 511) & ~size_t(511); }

// ---------- CSR build ----------

__global__ void count_kernel(const int* __restrict__ ei, int* __restrict__ cnt, int E){
  int e = blockIdx.x*256 + threadIdx.x;
  if (e < E) atomicAdd(&cnt[ei[E + e]], 1);
}

__global__ void dis_kernel(const int* __restrict__ cnt, float* __restrict__ dis, int N){
  int i = blockIdx.x*256 + threadIdx.x;
  if (i < N) dis[i] = rsqrtf((float)cnt[i] + 1.0f);
}

__global__ void scan_block_kernel(const int* __restrict__ cnt, int* __restrict__ rp,
                                  int* __restrict__ bsum, int N){
  __shared__ int s[2][1024];
  int t = threadIdx.x; int i = blockIdx.x*1024 + t;
  int v = (i < N) ? cnt[i] : 0;
  int cur = 0; s[0][t] = v; __syncthreads();
  for (int off = 1; off < 1024; off <<= 1){
    int nxt = cur ^ 1;
    int val = s[cur][t];
    if (t >= off) val += s[cur][t - off];
    s[nxt][t] = val; cur = nxt; __syncthreads();
  }
  if (i < N) rp[i+1] = s[cur][t];
  if (t == 1023) bsum[blockIdx.x] = s[cur][1023];
}

__global__ void scan_sums_kernel(int* __restrict__ bsum, int nb){
  __shared__ int s[128];
  int t = threadIdx.x;
  if (t < nb) s[t] = bsum[t];
  __syncthreads();
  if (t == 0){ int acc = 0; for (int b = 0; b < nb; b++){ int v = s[b]; s[b] = acc; acc += v; } }
  __syncthreads();
  if (t < nb) bsum[t] = s[t];
}

__global__ void add_off_kernel(int* __restrict__ rp, const int* __restrict__ bsum,
                               int* __restrict__ cnt, int N){
  int i = blockIdx.x*256 + threadIdx.x;
  if (i < N){ rp[i+1] += bsum[i >> 10]; cnt[i] = 0; }
  if (i == 0) rp[0] = 0;
}

__global__ void fill_kernel(const int* __restrict__ ei, const int* __restrict__ rp,
                            int* __restrict__ cnt, int* __restrict__ csrc, int E){
  int e = blockIdx.x*256 + threadIdx.x;
  if (e < E){
    int s = ei[e]; int d = ei[E + e];
    int pos = rp[d] + atomicAdd(&cnt[d], 1);
    csrc[pos] = s;
  }
}

// ---------- GEMM: out[N,256] = A[N,256] @ W[256,256] (no bias) ----------
// Register-blocked LDS tiling: BM=BN=128, BK=16, 256 threads, 8x8 out/thread
// as 2x2 blocks of 4x4 so all fragment reads are ds_read_b128, <=2-way banks.

__global__ __launch_bounds__(256) void gemm_kernel(const float* __restrict__ A,
                                                   const float* __restrict__ W,
                                                   float* __restrict__ out, int N){
  __shared__ float As[16][132];   // As[k][m]  (transposed A tile)
  __shared__ float Bs[16][132];   // Bs[k][c]
  int tid = threadIdx.x;
  int tx = tid & 15, ty = tid >> 4;
  int r0 = blockIdx.x * 128;
  int c0 = blockIdx.y * 128;

  // staging indices
  int am = tid >> 2;              // A: row within tile (0..63), 2 passes
  int ak = (tid & 3) << 2;        // A: k chunk (0,4,8,12)
  int bk = tid >> 5;              // B: k row (0..7), 2 passes
  int bc = (tid & 31) << 2;       // B: col chunk

  int arow0 = min(r0 + am, N - 1);
  int arow1 = min(r0 + 64 + am, N - 1);

  float4 acc[2][2][4];
  #pragma unroll
  for (int a = 0; a < 2; a++)
    #pragma unroll
    for (int b = 0; b < 2; b++)
      #pragma unroll
      for (int i = 0; i < 4; i++)
        acc[a][b][i] = make_float4(0.f, 0.f, 0.f, 0.f);

  for (int kb = 0; kb < 256; kb += 16){
    // stage A (transpose into As[k][m])
    float4 av0 = *(const float4*)&A[(size_t)arow0*256 + kb + ak];
    float4 av1 = *(const float4*)&A[(size_t)arow1*256 + kb + ak];
    As[ak+0][am]      = av0.x; As[ak+1][am]      = av0.y;
    As[ak+2][am]      = av0.z; As[ak+3][am]      = av0.w;
    As[ak+0][64+am]   = av1.x; As[ak+1][64+am]   = av1.y;
    As[ak+2][64+am]   = av1.z; As[ak+3][64+am]   = av1.w;
    // stage B
    float4 bv0 = *(const float4*)&W[(size_t)(kb + bk)*256 + c0 + bc];
    float4 bv1 = *(const float4*)&W[(size_t)(kb + bk + 8)*256 + c0 + bc];
    *(float4*)&Bs[bk][bc]     = bv0;
    *(float4*)&Bs[bk+8][bc]   = bv1;
    __syncthreads();

    #pragma unroll
    for (int k = 0; k < 16; k++){
      float4 a0 = *(const float4*)&As[k][ty*4];
      float4 a1 = *(const float4*)&As[k][64 + ty*4];
      float4 b0 = *(const float4*)&Bs[k][tx*4];
      float4 b1 = *(const float4*)&Bs[k][64 + tx*4];
      const float* ap0 = (const float*)&a0;
      const float* ap1 = (const float*)&a1;
      #pragma unroll
      for (int i = 0; i < 4; i++){
        float r0v = ap0[i], r1v = ap1[i];
        acc[0][0][i].x = fmaf(r0v, b0.x, acc[0][0][i].x);
        acc[0][0][i].y = fmaf(r0v, b0.y, acc[0][0][i].y);
        acc[0][0][i].z = fmaf(r0v, b0.z, acc[0][0][i].z);
        acc[0][0][i].w = fmaf(r0v, b0.w, acc[0][0][i].w);
        acc[0][1][i].x = fmaf(r0v, b1.x, acc[0][1][i].x);
        acc[0][1][i].y = fmaf(r0v, b1.y, acc[0][1][i].y);
        acc[0][1][i].z = fmaf(r0v, b1.z, acc[0][1][i].z);
        acc[0][1][i].w = fmaf(r0v, b1.w, acc[0][1][i].w);
        acc[1][0][i].x = fmaf(r1v, b0.x, acc[1][0][i].x);
        acc[1][0][i].y = fmaf(r1v, b0.y, acc[1][0][i].y);
        acc[1][0][i].z = fmaf(r1v, b0.z, acc[1][0][i].z);
        acc[1][0][i].w = fmaf(r1v, b0.w, acc[1][0][i].w);
        acc[1][1][i].x = fmaf(r1v, b1.x, acc[1][1][i].x);
        acc[1][1][i].y = fmaf(r1v, b1.y, acc[1][1][i].y);
        acc[1][1][i].z = fmaf(r1v, b1.z, acc[1][1][i].z);
        acc[1][1][i].w = fmaf(r1v, b1.w, acc[1][1][i].w);
      }
    }
    __syncthreads();
  }

  #pragma unroll
  for (int rb = 0; rb < 2; rb++){
    #pragma unroll
    for (int i = 0; i < 4; i++){
      int r = r0 + rb*64 + ty*4 + i;
      if (r < N){
        *(float4*)&out[(size_t)r*256 + c0 + tx*4]      = acc[rb][0][i];
        *(float4*)&out[(size_t)r*256 + c0 + 64 + tx*4] = acc[rb][1][i];
      }
    }
  }
}

// ---------- GCN aggregation: out[i] = relu( sum_{e: dst=i} dis[s]*dis[i]*xw[s]
//                                           + dis[i]^2 * xw[i] + bias ) ----------
// one wave per node, lane = 4 columns (float4); no float atomics (CSR gather).

__global__ __launch_bounds__(256) void agg_kernel(const float* __restrict__ xw,
                                                  const float* __restrict__ dis,
                                                  const int* __restrict__ rp,
                                                  const int* __restrict__ csrc,
                                                  const float* __restrict__ bias,
                                                  float* __restrict__ out, int N){
  int node = blockIdx.x*4 + (threadIdx.x >> 6);
  int lane = threadIdx.x & 63;
  if (node >= N) return;
  const float4* xw4 = (const float4*)xw;
  float di = dis[node];
  float4 a = xw4[(size_t)node*64 + lane];
  float sc = di * di;
  float4 acc;
  acc.x = a.x*sc; acc.y = a.y*sc; acc.z = a.z*sc; acc.w = a.w*sc;
  int e0 = rp[node], e1 = rp[node+1];
  for (int e = e0; e < e1; e++){
    int s = csrc[e];
    float cc = dis[s] * di;
    float4 v = xw4[(size_t)s*64 + lane];
    acc.x = fmaf(v.x, cc, acc.x);
    acc.y = fmaf(v.y, cc, acc.y);
    acc.z = fmaf(v.z, cc, acc.z);
    acc.w = fmaf(v.w, cc, acc.w);
  }
  const float4* b4 = (const float4*)bias;
  float4 b = b4[lane];
  acc.x = fmaxf(acc.x + b.x, 0.f);
  acc.y = fmaxf(acc.y + b.y, 0.f);
  acc.z = fmaxf(acc.z + b.z, 0.f);
  acc.w = fmaxf(acc.w + b.w, 0.f);
  ((float4*)out)[(size_t)node*64 + lane] = acc;
}

// ---------- mean pool over ptr segments (atomic partial sums into zeroed hp) ----------

__global__ void pool_kernel(const float* __restrict__ h, const int* __restrict__ ptr,
                            float* __restrict__ hp){
  int t = blockIdx.x; int part = blockIdx.y; int c = threadIdx.x;
  int s0 = ptr[t], s1 = ptr[t+1];
  int len = s1 - s0;
  int chunk = (len + 7) / 8;
  int r0 = s0 + part*chunk;
  int r1 = min(r0 + chunk, s1);
  float acc = 0.f;
  for (int r = r0; r < r1; r++) acc += h[(size_t)r*256 + c];
  if (r1 > r0) atomicAdd(&hp[t*256 + c], acc);
}

__global__ void hp_div_kernel(float* __restrict__ hp, const int* __restrict__ ptr){
  int t = blockIdx.x; int c = threadIdx.x;
  float cf = (float)max(ptr[t+1] - ptr[t], 1);
  hp[t*256 + c] /= cf;
}

// ---------- transpose w_hh [768,256] -> w_hhT [256,768] ----------

__global__ void twhh_kernel(const float* __restrict__ w, float* __restrict__ wt){
  int idx = blockIdx.x*256 + threadIdx.x;
  if (idx < 768*256){
    int k = idx / 768, g = idx % 768;
    wt[idx] = w[g*256 + k];
  }
}

// ---------- GX[t,g] = dot(hp[t], w_ih[g]) + b_ih[g] ----------

__global__ __launch_bounds__(768) void gx_kernel(const float* __restrict__ hp,
                                                 const float* __restrict__ wih,
                                                 const float* __restrict__ bih,
                                                 float* __restrict__ gx){
  __shared__ float xs[256];
  int t = blockIdx.x; int g = threadIdx.x;
  if (g < 256) xs[g] = hp[t*256 + g];
  __syncthreads();
  float acc = bih[g];
  const float* wr = wih + (size_t)g*256;
  #pragma unroll 4
  for (int k = 0; k < 256; k++) acc = fmaf(xs[k], wr[k], acc);
  gx[t*768 + g] = acc;
}

// ---------- sequential GRU (single block, 768 threads) + classifier ----------

__global__ __launch_bounds__(768) void gru_kernel(const float* __restrict__ gx,
                                                  const float* __restrict__ wt,
                                                  const float* __restrict__ bhh,
                                                  const float* __restrict__ Wc,
                                                  const float* __restrict__ bc,
                                                  float* __restrict__ out){
  __shared__ float hs[256];
  __shared__ float pl[4*768];
  int tid = threadIdx.x;
  int kq = tid / 192;
  int gq = tid % 192;
  if (tid < 256) hs[tid] = 0.f;
  __syncthreads();
  const float4* w4 = (const float4*)wt;
  for (int t = 0; t < 64; t++){
    float4 p = make_float4(0.f, 0.f, 0.f, 0.f);
    int kb = kq * 64;
    #pragma unroll 4
    for (int kk = 0; kk < 64; kk++){
      float hk = hs[kb + kk];
      float4 w = w4[(size_t)(kb + kk)*192 + gq];
      p.x = fmaf(hk, w.x, p.x);
      p.y = fmaf(hk, w.y, p.y);
      p.z = fmaf(hk, w.z, p.z);
      p.w = fmaf(hk, w.w, p.w);
    }
    ((float4*)pl)[kq*192 + gq] = p;   // pl[kq][g]
    __syncthreads();
    float hnew = 0.f;
    if (tid < 256){
      int i = tid;
      float hr = bhh[i], hz = bhh[i+256], hn = bhh[i+512];
      #pragma unroll
      for (int q = 0; q < 4; q++){
        hr += pl[q*768 + i];
        hz += pl[q*768 + i + 256];
        hn += pl[q*768 + i + 512];
      }
      float xr = gx[t*768 + i], xz = gx[t*768 + i + 256], xn = gx[t*768 + i + 512];
      float r = 1.f/(1.f + expf(-(xr + hr)));
      float z = 1.f/(1.f + expf(-(xz + hz)));
      float n = tanhf(xn + r*hn);
      hnew = (1.f - z)*n + z*hs[i];
    }
    __syncthreads();
    if (tid < 256) hs[tid] = hnew;
    __syncthreads();
  }
  if (tid < 16){
    float acc = bc[tid];
    const float* wr = Wc + (size_t)tid*256;
    for (int k = 0; k < 256; k++) acc = fmaf(hs[k], wr[k], acc);
    out[tid] = acc;
  }
}

extern "C" void kernel_launch(void* const* d_in, const int* in_sizes, int n_in,
                              void* d_out, int out_size, void* d_ws, size_t ws_size,
                              hipStream_t stream){
  const float* x   = (const float*)d_in[0];
  const int*   ei  = (const int*)d_in[1];
  const int*   ptr = (const int*)d_in[2];
  const float* W1  = (const float*)d_in[3];
  const float* b1  = (const float*)d_in[4];
  const float* W2  = (const float*)d_in[5];
  const float* b2  = (const float*)d_in[6];
  const float* wih = (const float*)d_in[7];
  const float* whh = (const float*)d_in[8];
  const float* bih = (const float*)d_in[9];
  const float* bhh = (const float*)d_in[10];
  const float* Wc  = (const float*)d_in[11];
  const float* bc  = (const float*)d_in[12];
  float* outp = (float*)d_out;

  const int N = in_sizes[0] / 256;   // 100000
  const int E = in_sizes[1] / 2;     // 1600000

  char* w = (char*)d_ws;
  size_t off = 0;
  auto alloc = [&](size_t bytes){ void* p = w + off; off = align512(off + bytes); return p; };
  float* bufA = (float*)alloc((size_t)N*256*4);   // xw
  float* bufB = (float*)alloc((size_t)N*256*4);   // h (post-agg)
  float* dis  = (float*)alloc((size_t)N*4);
  int*   cnt  = (int*)  alloc((size_t)N*4);
  int*   rp   = (int*)  alloc((size_t)(N+1)*4);
  int*   bsum = (int*)  alloc(128*4);
  int*   csrc = (int*)  alloc((size_t)E*4);
  float* wt   = (float*)alloc((size_t)768*256*4);
  float* hp   = (float*)alloc((size_t)64*256*4);
  float* gxb  = (float*)alloc((size_t)64*768*4);
  (void)ws_size; (void)n_in; (void)out_size;

  hipMemsetAsync(cnt, 0, (size_t)N*4, stream);
  hipMemsetAsync(hp,  0, (size_t)64*256*4, stream);

  // CSR build + degree
  count_kernel<<<(E+255)/256, 256, 0, stream>>>(ei, cnt, E);
  dis_kernel<<<(N+255)/256, 256, 0, stream>>>(cnt, dis, N);
  int nb = (N + 1023) / 1024;
  scan_block_kernel<<<nb, 1024, 0, stream>>>(cnt, rp, bsum, N);
  scan_sums_kernel<<<1, 128, 0, stream>>>(bsum, nb);
  add_off_kernel<<<(N+255)/256, 256, 0, stream>>>(rp, bsum, cnt, N);
  fill_kernel<<<(E+255)/256, 256, 0, stream>>>(ei, rp, cnt, csrc, E);
  twhh_kernel<<<(768*256+255)/256, 256, 0, stream>>>(whh, wt);

  // GCN layer 1
  gemm_kernel<<<dim3((N+127)/128, 2), 256, 0, stream>>>(x, W1, bufA, N);
  agg_kernel<<<(N+3)/4, 256, 0, stream>>>(bufA, dis, rp, csrc, b1, bufB, N);
  // GCN layer 2
  gemm_kernel<<<dim3((N+127)/128, 2), 256, 0, stream>>>(bufB, W2, bufA, N);
  agg_kernel<<<(N+3)/4, 256, 0, stream>>>(bufA, dis, rp, csrc, b2, bufB, N);

  // pool + GRU + classifier
  pool_kernel<<<dim3(64, 8), 256, 0, stream>>>(bufB, ptr, hp);
  hp_div_kernel<<<64, 256, 0, stream>>>(hp, ptr);
  gx_kernel<<<64, 768, 0, stream>>>(hp, wih, bih, gxb);
  gru_kernel<<<1, 768, 0, stream>>>(gxb, wt, bhh, Wc, bc, outp);
}